// Round 1
// baseline (935.447 us; speedup 1.0000x reference)
//
#include <hip/hip_runtime.h>
#include <math.h>

// Problem constants (B, F, T, K) = (4096, 2048, 16, 8)
#define B_TOT 4096
#define F_DIM 2048
#define T_DIM 16
#define K_DIM 8
#define NB    4          // batches per workgroup
#define SF    64         // f-columns of W staged per super-chunk
#define NSUP  (F_DIM / SF)   // 32 super-chunks
// logits[b,t,k] = sum_f h[b,f,t] * W[k,t,f] + bias[k,t];  out = sigmoid(logits), layout [B,T,K]

__global__ __launch_bounds__(256, 4)
void ta_kernel(const float* __restrict__ h, const float* __restrict__ W,
               const float* __restrict__ bias, float* __restrict__ out)
{
    // main loop: W tile 8*16*64 = 8192 floats; epilogue: 256*33 = 8448 floats
    __shared__ float smem[8448];

    const int tid  = threadIdx.x;
    const int t    = tid & 15;        // this thread's timestep
    const int fres = tid >> 4;        // f residue mod 16 (0..15)
    const int b0   = blockIdx.x * NB;

    float acc[NB][K_DIM];
#pragma unroll
    for (int nb = 0; nb < NB; ++nb)
#pragma unroll
        for (int k = 0; k < K_DIM; ++k) acc[nb][k] = 0.f;

    // h address: h[b][f][t] = b*32768 + f*16 + t ; with f = i*16+fres, t=tid&15:
    //   = b*32768 + i*256 + tid   -> contiguous 1KiB per wg per batch per iter
    const float* hbase = h + (size_t)b0 * (F_DIM * T_DIM) + tid;

    // W staging decode: thread (tw, j4) loads W[p][tw][f0 + 4*j4 .. +3] as float4
    const int tw  = tid >> 4;              // W row (t index), 0..15
    const int j4  = tid & 15;              // float4 index within 64-wide f chunk
    const int jsw = ((j4 + tw) & 15) * 4;  // swizzled LDS float4 slot (bank spread)
    const float* wg = W + tw * F_DIM + j4 * 4;
    const int xw = fres + 4 * t;           // read-side swizzle base

    // prefetch first W tile into registers
    float4 wreg[K_DIM];
#pragma unroll
    for (int p = 0; p < K_DIM; ++p)
        wreg[p] = *(const float4*)(wg + p * (T_DIM * F_DIM));

    for (int sc = 0; sc < NSUP; ++sc) {
        __syncthreads();                   // previous tile's readers done
#pragma unroll
        for (int p = 0; p < K_DIM; ++p)
            *(float4*)(&smem[p * 1024 + tw * 64 + jsw]) = wreg[p];
        __syncthreads();                   // tile visible

        if (sc + 1 < NSUP) {               // prefetch next tile (in flight during compute)
            const int f1 = (sc + 1) * SF;
#pragma unroll
            for (int p = 0; p < K_DIM; ++p)
                wreg[p] = *(const float4*)(wg + p * (T_DIM * F_DIM) + f1);
        }

#pragma unroll
        for (int il = 0; il < 4; ++il) {
            const int i = sc * 4 + il;     // global f-chunk index, f = i*16 + fres
            float hv[NB];
#pragma unroll
            for (int nb = 0; nb < NB; ++nb)
                hv[nb] = hbase[(size_t)nb * (F_DIM * T_DIM) + i * 256];

            float wv[K_DIM];
            const int idx = (il * 16 + xw) & 63;   // swizzled j position
#pragma unroll
            for (int k = 0; k < K_DIM; ++k)
                wv[k] = smem[k * 1024 + t * 64 + idx];

#pragma unroll
            for (int nb = 0; nb < NB; ++nb)
#pragma unroll
                for (int k = 0; k < K_DIM; ++k)
                    acc[nb][k] = fmaf(hv[nb], wv[k], acc[nb][k]);
        }
    }

    // ---- epilogue: reduce the 16 fres-partials per (t, nb, k), bias + sigmoid ----
    __syncthreads();                       // done reading W tile
    {
        float* r = &smem[tid * 33];        // stride 33: bank-conflict-free dump
#pragma unroll
        for (int nb = 0; nb < NB; ++nb)
#pragma unroll
            for (int k = 0; k < K_DIM; ++k)
                r[nb * 8 + k] = acc[nb][k];
    }
    __syncthreads();

#pragma unroll
    for (int rep = 0; rep < 2; ++rep) {    // 512 outputs, 256 threads
        const int o   = tid + rep * 256;
        const int nb  = o >> 7;            // T*K = 128
        const int rem = o & 127;
        const int tt  = rem >> 3;
        const int kk  = rem & 7;
        float s = 0.f;
#pragma unroll
        for (int fr = 0; fr < 16; ++fr)
            s += smem[(fr * 16 + tt) * 33 + nb * 8 + kk];
        s += bias[kk * T_DIM + tt];
        s = 1.0f / (1.0f + __expf(-s));
        out[(size_t)(b0 + nb) * (T_DIM * K_DIM) + rem] = s;
    }
}

extern "C" void kernel_launch(void* const* d_in, const int* in_sizes, int n_in,
                              void* d_out, int out_size, void* d_ws, size_t ws_size,
                              hipStream_t stream) {
    const float* h    = (const float*)d_in[0];   // [B, F, T] fp32
    const float* W    = (const float*)d_in[1];   // [K, T, F] fp32
    const float* bias = (const float*)d_in[2];   // [K, T] fp32
    float* out = (float*)d_out;                  // [B, T, K] fp32
    ta_kernel<<<dim3(B_TOT / NB), dim3(256), 0, stream>>>(h, W, bias, out);
}

// Round 2
// 692.260 us; speedup vs baseline: 1.3513x; 1.3513x over previous
//
#include <hip/hip_runtime.h>
#include <math.h>

// (B, F, T, K) = (4096, 2048, 16, 8)
// logits[b,t,k] = sum_f h[b,f,t] * W[k,t,f] + bias[k,t]; out = sigmoid(logits), [B,T,K]
#define B_TOT 4096
#define F_DIM 2048
#define T_DIM 16
#define K_DIM 8
#define NB    4            // batches per workgroup
#define SF    64           // f-columns of W per tile
#define NSUP  (F_DIM / SF) // 32 tiles

// Direct global->LDS DMA, 16B per lane. LDS dest must be wave-uniform base + lane*16.
__device__ __forceinline__ void gload_lds16(const float* g, float* l) {
    __builtin_amdgcn_global_load_lds(
        (const __attribute__((address_space(1))) void*)g,
        (__attribute__((address_space(3))) void*)l,
        16, 0, 0);
}

__global__ __launch_bounds__(256)
void ta_kernel(const float* __restrict__ h, const float* __restrict__ W,
               const float* __restrict__ bias, float* __restrict__ out)
{
    // 32 KB: W tile (8k x 16t x 64f, float4-swizzled). Reused by the epilogue.
    __shared__ float smem[8192];

    const int tid  = threadIdx.x;
    const int t    = tid & 15;        // this thread's timestep
    const int fres = tid >> 4;        // f residue mod 16
    const int b0   = blockIdx.x * NB;

    float acc[NB][K_DIM];
#pragma unroll
    for (int nb = 0; nb < NB; ++nb)
#pragma unroll
        for (int k = 0; k < K_DIM; ++k) acc[nb][k] = 0.f;

    // ---- W staging decode (global_load_lds): round r stages k=r. ----
    // Slot s = r*256 + tid -> (k=r, t_row=tid>>4, c=tid&15); swizzle c=(j4+t_row)&15.
    const int tl = tid >> 4;
    const int j4 = ((tid & 15) - tl) & 15;
    const float* wp = W + tl * F_DIM + j4 * 4;   // add r*32768 + sc*64 per load
    float* lp = smem + tid * 4;                   // add r*1024 per round

    // ---- ds_read word offsets, tile-invariant ----
    // word(k=0, il) = t*64 + ((il*4 + (fres>>2) + t)&15)*4 + (fres&3)
    int voff[4];
#pragma unroll
    for (int il = 0; il < 4; ++il)
        voff[il] = t * 64 + ((il * 4 + (fres >> 2) + t) & 15) * 4 + (fres & 3);

    // h[b][f][t]: addr = b*32768 + (sc*4+il)*256 + tid  (contiguous per wg)
    const float* hb = h + (size_t)b0 * (F_DIM * T_DIM) + tid;

    for (int sc = 0; sc < NSUP; ++sc) {
        __syncthreads();               // all waves done reading previous tile
        {
            const float* wpf = wp + sc * SF;
#pragma unroll
            for (int r = 0; r < K_DIM; ++r)
                gload_lds16(wpf + r * (T_DIM * F_DIM), lp + r * 1024);
        }
        __syncthreads();               // vmcnt drain -> tile complete + visible

#pragma unroll
        for (int il = 0; il < 4; ++il) {
            float hv[NB];
#pragma unroll
            for (int nb = 0; nb < NB; ++nb)
                hv[nb] = hb[nb * (F_DIM * T_DIM) + sc * 1024 + il * 256];

            float wv[K_DIM];
#pragma unroll
            for (int k = 0; k < K_DIM; ++k)
                wv[k] = smem[k * 1024 + voff[il]];

#pragma unroll
            for (int nb = 0; nb < NB; ++nb)
#pragma unroll
                for (int k = 0; k < K_DIM; ++k)
                    acc[nb][k] = fmaf(hv[nb], wv[k], acc[nb][k]);
        }
    }

    // ---- epilogue: reduce 16 fres-partials per (t,nb,k), bias + sigmoid ----
    __syncthreads();                   // done reading last W tile; reuse smem
#pragma unroll
    for (int nb = 0; nb < NB; ++nb)
#pragma unroll
        for (int k = 0; k < K_DIM; ++k)
            smem[(nb * 8 + k) * 256 + tid] = acc[nb][k];   // transposed dump
    __syncthreads();

#pragma unroll
    for (int rep = 0; rep < 2; ++rep) {    // 512 outputs, 256 threads
        const int o   = tid + rep * 256;
        const int nb  = o >> 7;            // T*K = 128 outputs per batch
        const int rem = o & 127;
        const int tt  = rem >> 3;
        const int kk  = rem & 7;
        float s = 0.f;
#pragma unroll
        for (int fr = 0; fr < 16; ++fr)
            s += smem[(nb * 8 + kk) * 256 + fr * 16 + tt];
        s += bias[kk * T_DIM + tt];
        s = 1.0f / (1.0f + __expf(-s));
        out[(size_t)(b0 + nb) * (T_DIM * K_DIM) + rem] = s;
    }
}

extern "C" void kernel_launch(void* const* d_in, const int* in_sizes, int n_in,
                              void* d_out, int out_size, void* d_ws, size_t ws_size,
                              hipStream_t stream) {
    const float* h    = (const float*)d_in[0];   // [B, F, T] fp32
    const float* W    = (const float*)d_in[1];   // [K, T, F] fp32
    const float* bias = (const float*)d_in[2];   // [K, T] fp32
    float* out = (float*)d_out;                  // [B, T, K] fp32
    ta_kernel<<<dim3(B_TOT / NB), dim3(256), 0, stream>>>(h, W, bias, out);
}